// Round 3
// baseline (269.124 us; speedup 1.0000x reference)
//
#include <hip/hip_runtime.h>
#include <math.h>

#define NFFT  4096
#define LROW  2048
#define GLEN  298   // len(rev(w1)*rev(w1)*rev(wl)) = 100+100+100-2
#define HLEN  199   // len(rev(w1)*rev(w1))
#define OFF   1172
#define NEG2PI_D (-6.283185307179586476925286766559)
#define NEG2PI_F (-6.28318530717958647692f)

// LDS padding: +1 float every 32 -> strided FFT writes spread across banks
__device__ __forceinline__ int pad(int i) { return i + (i >> 5); }

// ---------------------------------------------------------------------------
// Kernel A: g = rev(w1)*rev(w1)*rev(wl)  (298 taps), then G[k] = DFT_4096(g)[k]/4096
// grid = 16 blocks x 256 threads; each thread produces one G[k].
// Twiddle recurrence in double: 298-step fp32 recurrence would drift ~2e-5.
// ---------------------------------------------------------------------------
__global__ __launch_bounds__(256)
void prep_g_kernel(const float* __restrict__ w1r, const float* __restrict__ w1i,
                   const float* __restrict__ wlr, const float* __restrict__ wli,
                   float2* __restrict__ G) {
  __shared__ float hr[HLEN], hs[HLEN], gr[GLEN], gi[GLEN];
  const int tid = threadIdx.x;
  // h = rev(w1) * rev(w1); a[i] = w1[99-i]
  for (int n = tid; n < HLEN; n += 256) {
    float sr = 0.f, si = 0.f;
    const int lo = n > 99 ? n - 99 : 0;
    const int hh = n < 99 ? n : 99;
    for (int i = lo; i <= hh; ++i) {
      const float ar = w1r[99 - i],        ai = w1i[99 - i];
      const float br = w1r[99 - (n - i)],  bi = w1i[99 - (n - i)];
      sr += ar * br - ai * bi;
      si += ar * bi + ai * br;
    }
    hr[n] = sr; hs[n] = si;
  }
  __syncthreads();
  // g = h * rev(wl)
  for (int n = tid; n < GLEN; n += 256) {
    float sr = 0.f, si = 0.f;
    const int lo = n > 99 ? n - 99 : 0;     // need 0 <= n-i <= 99
    const int hh = n < 198 ? n : 198;
    for (int i = lo; i <= hh; ++i) {
      const float ar = hr[i],              ai = hs[i];
      const float br = wlr[99 - (n - i)],  bi = wli[99 - (n - i)];
      sr += ar * br - ai * bi;
      si += ar * bi + ai * br;
    }
    gr[n] = sr; gi[n] = si;
  }
  __syncthreads();
  // G[k] = (1/N) * sum_m g[m] * W^(k*m),  W = exp(-2*pi*i/N)
  const int k = blockIdx.x * 256 + tid;
  double s, c;
  sincos(NEG2PI_D * (double)k / (double)NFFT, &s, &c);
  double cr = 1.0, ci = 0.0, accr = 0.0, acci = 0.0;
  for (int m = 0; m < GLEN; ++m) {
    const double a = (double)gr[m], b = (double)gi[m];
    accr += a * cr - b * ci;
    acci += a * ci + b * cr;
    const double t = cr * c - ci * s;
    ci = cr * s + ci * c;
    cr = t;
  }
  const double inv = 1.0 / (double)NFFT;
  G[k] = make_float2((float)(accr * inv), (float)(acci * inv));
}

// ---------------------------------------------------------------------------
// 4096-point radix-4 Stockham autosort FFT in LDS.
// 6 stages; reads are always contiguous (idx = b + p*1024); result lands back
// in the (sR,sI) buffers after the even number of ping-pong swaps.
// ---------------------------------------------------------------------------
__device__ __forceinline__ void fft4096(float* sR, float* sI, float* dR, float* dI,
                                        const float* __restrict__ Twr,
                                        const float* __restrict__ Twi, int tid) {
  int sh = 0;  // log2(m); m = 4^stage
  for (int s = 0; s < 6; ++s) {
    #pragma unroll
    for (int u = 0; u < 4; ++u) {
      const int b = tid + (u << 8);      // butterfly index in [0,1024)
      const int m = 1 << sh;
      const int j = b >> sh;             // j in [0,l), l = 1024/m
      const int k = b & (m - 1);
      const float c0r = sR[pad(b)],        c0i = sI[pad(b)];
      const float c1r = sR[pad(b + 1024)], c1i = sI[pad(b + 1024)];
      const float c2r = sR[pad(b + 2048)], c2i = sI[pad(b + 2048)];
      const float c3r = sR[pad(b + 3072)], c3i = sI[pad(b + 3072)];
      const int tix = j << sh;           // j * 4^s  -> index into W^j/4096 table
      const float wr = Twr[pad(tix)], wi = Twi[pad(tix)];
      const float w2r = wr * wr - wi * wi,  w2i = 2.f * wr * wi;
      const float w3r = w2r * wr - w2i * wi, w3i = w2r * wi + w2i * wr;
      const float d0r = c0r + c2r, d0i = c0i + c2i;
      const float d1r = c0r - c2r, d1i = c0i - c2i;
      const float d2r = c1r + c3r, d2i = c1i + c3i;
      const float d3r = c1i - c3i, d3i = c3r - c1r;   // -i*(c1-c3)
      const int base = k + (j << (sh + 2));           // k + 4*m*j
      dR[pad(base)] = d0r + d2r;
      dI[pad(base)] = d0i + d2i;
      const float e1r = d1r + d3r, e1i = d1i + d3i;
      dR[pad(base + m)] = wr * e1r - wi * e1i;
      dI[pad(base + m)] = wr * e1i + wi * e1r;
      const float e2r = d0r - d2r, e2i = d0i - d2i;
      dR[pad(base + 2 * m)] = w2r * e2r - w2i * e2i;
      dI[pad(base + 2 * m)] = w2r * e2i + w2i * e2r;
      const float e3r = d1r - d3r, e3i = d1i - d3i;
      dR[pad(base + 3 * m)] = w3r * e3r - w3i * e3i;
      dI[pad(base + 3 * m)] = w3r * e3i + w3i * e3r;
    }
    __syncthreads();
    float* t;
    t = sR; sR = dR; dR = t;
    t = sI; sI = dI; dI = t;
    sh += 2;
  }
}

// ---------------------------------------------------------------------------
// Kernel B: one row per block. FFT -> Z = X^2*G (1/N folded into G) ->
// store conj(Z) -> FFT again (= conj of IDFT) -> |.| of window [1172,3220).
// ---------------------------------------------------------------------------
__global__ __launch_bounds__(256)
void fft_conv_kernel(const float* __restrict__ xr, const float* __restrict__ xi,
                     const float2* __restrict__ G, float* __restrict__ out) {
  __shared__ float Ar[4224], Ai[4224], Br[4224], Bi[4224];
  __shared__ float Twr[1056], Twi[1056];
  const int tid = threadIdx.x;
  const int row = blockIdx.x;

  // twiddle table: Tw[j] = exp(-2*pi*i*j/4096), j in [0,1024)
  for (int j = tid; j < 1024; j += 256) {
    float s, c;
    sincosf(NEG2PI_F * (float)j * (1.0f / (float)NFFT), &s, &c);
    Twr[pad(j)] = c; Twi[pad(j)] = s;
  }
  // load row, zero-pad 2048..4095
  const float* xrr = xr + (size_t)row * LROW;
  const float* xir = xi + (size_t)row * LROW;
  for (int n = tid; n < LROW; n += 256) {
    Ar[pad(n)] = xrr[n];
    Ai[pad(n)] = xir[n];
  }
  for (int n = LROW + tid; n < NFFT; n += 256) {
    Ar[pad(n)] = 0.f;
    Ai[pad(n)] = 0.f;
  }
  __syncthreads();

  fft4096(Ar, Ai, Br, Bi, Twr, Twi, tid);      // X in A

  // Z = X^2 * G  (G already has 1/N); store conj(Z)
  for (int k = tid; k < NFFT; k += 256) {
    const float xre = Ar[pad(k)], xim = Ai[pad(k)];
    const float x2r = xre * xre - xim * xim;
    const float x2i = 2.f * xre * xim;
    const float2 g = G[k];
    const float zr = x2r * g.x - x2i * g.y;
    const float zi = x2r * g.y + x2i * g.x;
    Ar[pad(k)] = zr;
    Ai[pad(k)] = -zi;
  }
  __syncthreads();

  fft4096(Ar, Ai, Br, Bi, Twr, Twi, tid);      // conj(IDFT(Z)) in A; |.| kills conj

  float* orow = out + (size_t)row * LROW;
  for (int n = tid; n < LROW; n += 256) {
    const float zr = Ar[pad(n + OFF)], zi = Ai[pad(n + OFF)];
    orow[n] = sqrtf(zr * zr + zi * zi);
  }
}

// ---------------------------------------------------------------------------
extern "C" void kernel_launch(void* const* d_in, const int* in_sizes, int n_in,
                              void* d_out, int out_size, void* d_ws, size_t ws_size,
                              hipStream_t stream) {
  const float* xr  = (const float*)d_in[0];
  const float* xi  = (const float*)d_in[1];
  const float* w1r = (const float*)d_in[2];
  const float* w1i = (const float*)d_in[3];
  const float* wlr = (const float*)d_in[4];
  const float* wli = (const float*)d_in[5];
  float* out = (float*)d_out;
  float2* G = (float2*)d_ws;                 // 4096 * 8 B = 32 KB scratch
  const int rows = in_sizes[0] / LROW;       // 4096

  prep_g_kernel<<<NFFT / 256, 256, 0, stream>>>(w1r, w1i, wlr, wli, G);
  fft_conv_kernel<<<rows, 256, 0, stream>>>(xr, xi, G, out);
}

// Round 4
// 253.602 us; speedup vs baseline: 1.0612x; 1.0612x over previous
//
#include <hip/hip_runtime.h>
#include <math.h>

#define NFFT  4096
#define LROW  2048
#define GLEN  298   // len(rev(w1)*rev(w1)*rev(wl)) = 100+100+100-2
#define HLEN  199   // len(rev(w1)*rev(w1))
#define OFF   1172
#define NEG2PI_D (-6.283185307179586476925286766559)
#define NEG2PI_F (-6.28318530717958647692f)

// float2 LDS padding: +1 element every 16 (=128B) -> strided writes spread banks
__device__ __forceinline__ int pad2(int i) { return i + (i >> 4); }

// ---------------------------------------------------------------------------
// Kernel A: g = rev(w1)*rev(w1)*rev(wl)  (298 taps), then G[k] = DFT_4096(g)[k]/4096
// grid = 16 blocks x 256 threads; each thread produces one G[k].
// Twiddle recurrence in double: 298-step fp32 recurrence would drift ~2e-5.
// ---------------------------------------------------------------------------
__global__ __launch_bounds__(256)
void prep_g_kernel(const float* __restrict__ w1r, const float* __restrict__ w1i,
                   const float* __restrict__ wlr, const float* __restrict__ wli,
                   float2* __restrict__ G) {
  __shared__ float hr[HLEN], hs[HLEN], gr[GLEN], gi[GLEN];
  const int tid = threadIdx.x;
  // h = rev(w1) * rev(w1); a[i] = w1[99-i]
  for (int n = tid; n < HLEN; n += 256) {
    float sr = 0.f, si = 0.f;
    const int lo = n > 99 ? n - 99 : 0;
    const int hh = n < 99 ? n : 99;
    for (int i = lo; i <= hh; ++i) {
      const float ar = w1r[99 - i],        ai = w1i[99 - i];
      const float br = w1r[99 - (n - i)],  bi = w1i[99 - (n - i)];
      sr += ar * br - ai * bi;
      si += ar * bi + ai * br;
    }
    hr[n] = sr; hs[n] = si;
  }
  __syncthreads();
  // g = h * rev(wl)
  for (int n = tid; n < GLEN; n += 256) {
    float sr = 0.f, si = 0.f;
    const int lo = n > 99 ? n - 99 : 0;     // need 0 <= n-i <= 99
    const int hh = n < 198 ? n : 198;
    for (int i = lo; i <= hh; ++i) {
      const float ar = hr[i],              ai = hs[i];
      const float br = wlr[99 - (n - i)],  bi = wli[99 - (n - i)];
      sr += ar * br - ai * bi;
      si += ar * bi + ai * br;
    }
    gr[n] = sr; gi[n] = si;
  }
  __syncthreads();
  // G[k] = (1/N) * sum_m g[m] * W^(k*m),  W = exp(-2*pi*i/N)
  const int k = blockIdx.x * 256 + tid;
  double s, c;
  sincos(NEG2PI_D * (double)k / (double)NFFT, &s, &c);
  double cr = 1.0, ci = 0.0, accr = 0.0, acci = 0.0;
  for (int m = 0; m < GLEN; ++m) {
    const double a = (double)gr[m], b = (double)gi[m];
    accr += a * cr - b * ci;
    acci += a * ci + b * cr;
    const double t = cr * c - ci * s;
    ci = cr * s + ci * c;
    cr = t;
  }
  const double inv = 1.0 / (double)NFFT;
  G[k] = make_float2((float)(accr * inv), (float)(acci * inv));
}

// ---------------------------------------------------------------------------
// 4096-point radix-4 Stockham autosort FFT in LDS, float2 element (b64 ds ops).
// 6 stages; reads always contiguous; result lands back in s after 6 swaps.
// 512 threads: 2 butterflies per thread per stage.
// ---------------------------------------------------------------------------
__device__ __forceinline__ void fft4096(float2* s, float2* d,
                                        const float2* __restrict__ Tw, int tid) {
  int sh = 0;  // log2(m); m = 4^stage
  for (int st = 0; st < 6; ++st) {
    #pragma unroll
    for (int u = 0; u < 2; ++u) {
      const int b = tid + (u << 9);      // butterfly index in [0,1024)
      const int m = 1 << sh;
      const int j = b >> sh;             // j in [0,l), l = 1024/m
      const int k = b & (m - 1);
      const float2 c0 = s[pad2(b)];
      const float2 c1 = s[pad2(b + 1024)];
      const float2 c2 = s[pad2(b + 2048)];
      const float2 c3 = s[pad2(b + 3072)];
      const float2 w = Tw[pad2(j << sh)];            // W^(j*4^st) / 4096
      const float wr = w.x, wi = w.y;
      const float w2r = wr * wr - wi * wi,  w2i = 2.f * wr * wi;
      const float w3r = w2r * wr - w2i * wi, w3i = w2r * wi + w2i * wr;
      const float d0r = c0.x + c2.x, d0i = c0.y + c2.y;
      const float d1r = c0.x - c2.x, d1i = c0.y - c2.y;
      const float d2r = c1.x + c3.x, d2i = c1.y + c3.y;
      const float d3r = c1.y - c3.y, d3i = c3.x - c1.x;   // -i*(c1-c3)
      const int base = k + (j << (sh + 2));               // k + 4*m*j
      d[pad2(base)] = make_float2(d0r + d2r, d0i + d2i);
      const float e1r = d1r + d3r, e1i = d1i + d3i;
      d[pad2(base + m)] = make_float2(wr * e1r - wi * e1i, wr * e1i + wi * e1r);
      const float e2r = d0r - d2r, e2i = d0i - d2i;
      d[pad2(base + 2 * m)] = make_float2(w2r * e2r - w2i * e2i, w2r * e2i + w2i * e2r);
      const float e3r = d1r - d3r, e3i = d1i - d3i;
      d[pad2(base + 3 * m)] = make_float2(w3r * e3r - w3i * e3i, w3r * e3i + w3i * e3r);
    }
    __syncthreads();
    float2* t = s; s = d; d = t;
    sh += 2;
  }
}

// ---------------------------------------------------------------------------
// Kernel B: one row per block (512 threads). FFT -> Z = X^2*G (1/N in G) ->
// store conj(Z) -> FFT again (= conj of IDFT) -> |.| of window [1172,3220).
// ---------------------------------------------------------------------------
__global__ __launch_bounds__(512)
void fft_conv_kernel(const float* __restrict__ xr, const float* __restrict__ xi,
                     const float2* __restrict__ G, float* __restrict__ out) {
  __shared__ float2 A[4352], Bb[4352];     // pad2(4095)=4350
  __shared__ float2 Tw[1088];              // pad2(1023)=1086
  const int tid = threadIdx.x;
  const int row = blockIdx.x;

  // twiddle table: Tw[j] = exp(-2*pi*i*j/4096), j in [0,1024)
  for (int j = tid; j < 1024; j += 512) {
    float s, c;
    sincosf(NEG2PI_F * (float)j * (1.0f / (float)NFFT), &s, &c);
    Tw[pad2(j)] = make_float2(c, s);
  }
  // load row, zero-pad 2048..4095
  const float* xrr = xr + (size_t)row * LROW;
  const float* xir = xi + (size_t)row * LROW;
  for (int n = tid; n < LROW; n += 512)
    A[pad2(n)] = make_float2(xrr[n], xir[n]);
  for (int n = LROW + tid; n < NFFT; n += 512)
    A[pad2(n)] = make_float2(0.f, 0.f);
  __syncthreads();

  fft4096(A, Bb, Tw, tid);                 // X in A

  // Z = X^2 * G  (G already has 1/N); store conj(Z)
  for (int k = tid; k < NFFT; k += 512) {
    const float2 x = A[pad2(k)];
    const float x2r = x.x * x.x - x.y * x.y;
    const float x2i = 2.f * x.x * x.y;
    const float2 g = G[k];
    A[pad2(k)] = make_float2(x2r * g.x - x2i * g.y, -(x2r * g.y + x2i * g.x));
  }
  __syncthreads();

  fft4096(A, Bb, Tw, tid);                 // conj(IDFT(Z)) in A; |.| kills conj

  float* orow = out + (size_t)row * LROW;
  for (int n = tid; n < LROW; n += 512) {
    const float2 z = A[pad2(n + OFF)];
    orow[n] = sqrtf(z.x * z.x + z.y * z.y);
  }
}

// ---------------------------------------------------------------------------
extern "C" void kernel_launch(void* const* d_in, const int* in_sizes, int n_in,
                              void* d_out, int out_size, void* d_ws, size_t ws_size,
                              hipStream_t stream) {
  const float* xr  = (const float*)d_in[0];
  const float* xi  = (const float*)d_in[1];
  const float* w1r = (const float*)d_in[2];
  const float* w1i = (const float*)d_in[3];
  const float* wlr = (const float*)d_in[4];
  const float* wli = (const float*)d_in[5];
  float* out = (float*)d_out;
  float2* G = (float2*)d_ws;                 // 4096 * 8 B = 32 KB scratch
  const int rows = in_sizes[0] / LROW;       // 4096

  prep_g_kernel<<<NFFT / 256, 256, 0, stream>>>(w1r, w1i, wlr, wli, G);
  fft_conv_kernel<<<rows, 512, 0, stream>>>(xr, xi, G, out);
}

// Round 5
// 180.116 us; speedup vs baseline: 1.4942x; 1.4080x over previous
//
#include <hip/hip_runtime.h>
#include <math.h>

#define NFFT  4096
#define LROW  2048
#define GLEN  298   // len(rev(w1)*rev(w1)*rev(wl)) = 100+100+100-2
#define HLEN  199   // len(rev(w1)*rev(w1))
#define OFF   1172
#define NEG2PI_D (-6.283185307179586476925286766559)
#define NEG2PI_F (-6.28318530717958647692f)
#define RSQ2  0.70710678118654752440f

// float2 LDS padding: +1 element every 16 (=128B). Verified for radix-8
// strides M=1,8,64,512: every 16-lane b64 row covers 16 distinct bank pairs.
__device__ __forceinline__ int pad2(int i) { return i + (i >> 4); }

__device__ __forceinline__ float2 cadd(float2 a, float2 b) { return make_float2(a.x + b.x, a.y + b.y); }
__device__ __forceinline__ float2 csub(float2 a, float2 b) { return make_float2(a.x - b.x, a.y - b.y); }
__device__ __forceinline__ float2 cmul(float2 a, float2 b) {
  return make_float2(a.x * b.x - a.y * b.y, a.x * b.y + a.y * b.x);
}
// multiply by -i
__device__ __forceinline__ float2 cmni(float2 a) { return make_float2(a.y, -a.x); }

// DFT4 (W4 = -i):  F = [a+c + (b+d), (a-c) -i(b-d), a+c - (b+d), (a-c) +i(b-d)]
__device__ __forceinline__ void dft4(float2 a, float2 b, float2 c, float2 d,
                                     float2& F0, float2& F1, float2& F2, float2& F3) {
  const float2 s0 = cadd(a, c), s1 = csub(a, c);
  const float2 s2 = cadd(b, d), s3 = cmni(csub(b, d));
  F0 = cadd(s0, s2); F1 = cadd(s1, s3); F2 = csub(s0, s2); F3 = csub(s1, s3);
}

// 8-point DFT (DIT even/odd), e[t] = sum_u c[u] * W8^(u*t), W8 = (1-i)/sqrt(2)
__device__ __forceinline__ void bf8(const float2 c[8], float2 e[8]) {
  float2 E0, E1, E2, E3, O0, O1, O2, O3;
  dft4(c[0], c[2], c[4], c[6], E0, E1, E2, E3);
  dft4(c[1], c[3], c[5], c[7], O0, O1, O2, O3);
  const float2 u0 = O0;
  const float2 u1 = make_float2(RSQ2 * (O1.x + O1.y), RSQ2 * (O1.y - O1.x)); // *W8
  const float2 u2 = cmni(O2);                                               // *W8^2
  const float2 u3 = make_float2(RSQ2 * (O3.y - O3.x), -RSQ2 * (O3.x + O3.y)); // *W8^3
  e[0] = cadd(E0, u0); e[4] = csub(E0, u0);
  e[1] = cadd(E1, u1); e[5] = csub(E1, u1);
  e[2] = cadd(E2, u2); e[6] = csub(E2, u2);
  e[3] = cadd(E3, u3); e[7] = csub(E3, u3);
}

// ---------------------------------------------------------------------------
// Kernel A: g = rev(w1)*rev(w1)*rev(wl) (298 taps); G[k] = DFT_4096(g)[k]/4096
// ---------------------------------------------------------------------------
__global__ __launch_bounds__(256)
void prep_g_kernel(const float* __restrict__ w1r, const float* __restrict__ w1i,
                   const float* __restrict__ wlr, const float* __restrict__ wli,
                   float2* __restrict__ G) {
  __shared__ float hr[HLEN], hs[HLEN], gr[GLEN], gi[GLEN];
  const int tid = threadIdx.x;
  for (int n = tid; n < HLEN; n += 256) {
    float sr = 0.f, si = 0.f;
    const int lo = n > 99 ? n - 99 : 0;
    const int hh = n < 99 ? n : 99;
    for (int i = lo; i <= hh; ++i) {
      const float ar = w1r[99 - i],       ai = w1i[99 - i];
      const float br = w1r[99 - (n - i)], bi = w1i[99 - (n - i)];
      sr += ar * br - ai * bi;
      si += ar * bi + ai * br;
    }
    hr[n] = sr; hs[n] = si;
  }
  __syncthreads();
  for (int n = tid; n < GLEN; n += 256) {
    float sr = 0.f, si = 0.f;
    const int lo = n > 99 ? n - 99 : 0;
    const int hh = n < 198 ? n : 198;
    for (int i = lo; i <= hh; ++i) {
      const float ar = hr[i],             ai = hs[i];
      const float br = wlr[99 - (n - i)], bi = wli[99 - (n - i)];
      sr += ar * br - ai * bi;
      si += ar * bi + ai * br;
    }
    gr[n] = sr; gi[n] = si;
  }
  __syncthreads();
  const int k = blockIdx.x * 256 + tid;
  double s, c;
  sincos(NEG2PI_D * (double)k / (double)NFFT, &s, &c);
  double cr = 1.0, ci = 0.0, accr = 0.0, acci = 0.0;
  for (int m = 0; m < GLEN; ++m) {
    const double a = (double)gr[m], b = (double)gi[m];
    accr += a * cr - b * ci;
    acci += a * ci + b * cr;
    const double t = cr * c - ci * s;
    ci = cr * s + ci * c;
    cr = t;
  }
  const double inv = 1.0 / (double)NFFT;
  G[k] = make_float2((float)(accr * inv), (float)(acci * inv));
}

// ---------------------------------------------------------------------------
// Radix-8 Stockham middle stage, compile-time SH (M = 8^s = 1<<SH).
// Reads contiguous at b + t*512; writes at k + 8*M*j + M*t; twiddle w = W^(j*M)
// = Tw[b & ~(M-1)] (index < 512). Powers w^2..w^7 by chain (err ~7eps).
// ---------------------------------------------------------------------------
template <int SH>
__device__ __forceinline__ void mid_stage(const float2* __restrict__ S,
                                          float2* __restrict__ D,
                                          const float2* __restrict__ Tw, int b) {
  float2 c[8];
  #pragma unroll
  for (int t = 0; t < 8; ++t) c[t] = S[pad2(b + (t << 9))];
  float2 e[8];
  bf8(c, e);
  const int M = 1 << SH;
  const int j = b >> SH;
  const int k = b & (M - 1);
  const float2 w  = Tw[b & ~(M - 1)];
  const float2 w2 = cmul(w, w);
  const float2 w3 = cmul(w2, w);
  const float2 w4 = cmul(w2, w2);
  const float2 w5 = cmul(w2, w3);
  const float2 w6 = cmul(w3, w3);
  const float2 w7 = cmul(w3, w4);
  const int base = k + (j << (SH + 3));
  D[pad2(base)]           = e[0];
  D[pad2(base + M)]       = cmul(w,  e[1]);
  D[pad2(base + 2 * M)]   = cmul(w2, e[2]);
  D[pad2(base + 3 * M)]   = cmul(w3, e[3]);
  D[pad2(base + 4 * M)]   = cmul(w4, e[4]);
  D[pad2(base + 5 * M)]   = cmul(w5, e[5]);
  D[pad2(base + 6 * M)]   = cmul(w6, e[6]);
  D[pad2(base + 7 * M)]   = cmul(w7, e[7]);
}

// ---------------------------------------------------------------------------
// Kernel B: one row per block, 512 threads, radix-8 Stockham x2 with fused
// ends: global->stage0 (upper half zero), stage3+pointwise (twiddle-free,
// in-index), stage3'->|.|->global (twiddle-free, windowed).
// ---------------------------------------------------------------------------
__global__ __launch_bounds__(512, 4)
void fft_conv_kernel(const float* __restrict__ xr, const float* __restrict__ xi,
                     const float2* __restrict__ G, float* __restrict__ out) {
  __shared__ float2 A[4352], Bb[4352];   // pad2(4095) = 4350
  __shared__ float2 Tw[512];             // W_4096^j, j in [0,512) (unpadded)
  const int b = threadIdx.x;             // butterfly index, one per thread
  const int row = blockIdx.x;

  {  // twiddle table
    float s, c;
    sincosf(NEG2PI_F * (float)b * (1.0f / (float)NFFT), &s, &c);
    Tw[b] = make_float2(c, s);
  }
  __syncthreads();

  // ---- FFT1 stage 0 (SH=0): global reads, c4..c7 = 0 (zero-pad folds out)
  {
    const float* xrr = xr + (size_t)row * LROW;
    const float* xir = xi + (size_t)row * LROW;
    float2 c[8];
    #pragma unroll
    for (int t = 0; t < 4; ++t) c[t] = make_float2(xrr[b + (t << 9)], xir[b + (t << 9)]);
    #pragma unroll
    for (int t = 4; t < 8; ++t) c[t] = make_float2(0.f, 0.f);
    float2 e[8];
    bf8(c, e);
    const float2 w  = Tw[b];
    const float2 w2 = cmul(w, w),  w3 = cmul(w2, w), w4 = cmul(w2, w2);
    const float2 w5 = cmul(w2, w3), w6 = cmul(w3, w3), w7 = cmul(w3, w4);
    const int base = b << 3;           // k=0, j=b, M=1
    A[pad2(base)]     = e[0];
    A[pad2(base + 1)] = cmul(w,  e[1]);
    A[pad2(base + 2)] = cmul(w2, e[2]);
    A[pad2(base + 3)] = cmul(w3, e[3]);
    A[pad2(base + 4)] = cmul(w4, e[4]);
    A[pad2(base + 5)] = cmul(w5, e[5]);
    A[pad2(base + 6)] = cmul(w6, e[6]);
    A[pad2(base + 7)] = cmul(w7, e[7]);
  }
  __syncthreads();
  mid_stage<3>(A, Bb, Tw, b);  __syncthreads();   // FFT1 stage 1
  mid_stage<6>(Bb, A, Tw, b);  __syncthreads();   // FFT1 stage 2

  // ---- FFT1 stage 3 (SH=9: j=0, twiddle-free, read idx == write idx)
  // fused pointwise: Z = X^2*G (1/N in G); store conj(Z) for FFT2
  {
    float2 c[8];
    #pragma unroll
    for (int t = 0; t < 8; ++t) c[t] = A[pad2(b + (t << 9))];
    float2 e[8];
    bf8(c, e);
    #pragma unroll
    for (int t = 0; t < 8; ++t) {
      const int idx = b + (t << 9);
      const float2 x = e[t];
      const float2 x2 = make_float2(x.x * x.x - x.y * x.y, 2.f * x.x * x.y);
      const float2 z = cmul(x2, G[idx]);
      Bb[pad2(idx)] = make_float2(z.x, -z.y);
    }
  }
  __syncthreads();
  mid_stage<0>(Bb, A, Tw, b);  __syncthreads();   // FFT2 stage 0
  mid_stage<3>(A, Bb, Tw, b);  __syncthreads();   // FFT2 stage 1
  mid_stage<6>(Bb, A, Tw, b);  __syncthreads();   // FFT2 stage 2

  // ---- FFT2 stage 3 (twiddle-free): |e_t| straight to global, windowed.
  // pos = b + 512t; window [1172, 3220): t=2 (b>=148), t=3,4,5 (all), t=6 (b<148)
  {
    float2 c[8];
    #pragma unroll
    for (int t = 0; t < 8; ++t) c[t] = A[pad2(b + (t << 9))];
    float2 e[8];
    bf8(c, e);
    float* orow = out + (size_t)row * LROW;
    if (b >= 148) orow[b + 1024 - OFF] = sqrtf(e[2].x * e[2].x + e[2].y * e[2].y);
    orow[b + 1536 - OFF] = sqrtf(e[3].x * e[3].x + e[3].y * e[3].y);
    orow[b + 2048 - OFF] = sqrtf(e[4].x * e[4].x + e[4].y * e[4].y);
    orow[b + 2560 - OFF] = sqrtf(e[5].x * e[5].x + e[5].y * e[5].y);
    if (b < 148)  orow[b + 3072 - OFF] = sqrtf(e[6].x * e[6].x + e[6].y * e[6].y);
  }
}

// ---------------------------------------------------------------------------
extern "C" void kernel_launch(void* const* d_in, const int* in_sizes, int n_in,
                              void* d_out, int out_size, void* d_ws, size_t ws_size,
                              hipStream_t stream) {
  const float* xr  = (const float*)d_in[0];
  const float* xi  = (const float*)d_in[1];
  const float* w1r = (const float*)d_in[2];
  const float* w1i = (const float*)d_in[3];
  const float* wlr = (const float*)d_in[4];
  const float* wli = (const float*)d_in[5];
  float* out = (float*)d_out;
  float2* G = (float2*)d_ws;                 // 4096 * 8 B = 32 KB scratch
  const int rows = in_sizes[0] / LROW;       // 4096

  prep_g_kernel<<<NFFT / 256, 256, 0, stream>>>(w1r, w1i, wlr, wli, G);
  fft_conv_kernel<<<rows, 512, 0, stream>>>(xr, xi, G, out);
}